// Round 8
// baseline (126.615 us; speedup 1.0000x reference)
//
#include <hip/hip_runtime.h>
#include <hip/hip_fp16.h>
#include <math.h>

#define N_PTS   8192
#define ENC     384
#define NTHREAD 384
#define NCELL1  8
#define NCELLS  512
#define RADIUS  0.12f

typedef _Float16 f16x8 __attribute__((ext_vector_type(8)));
typedef float    f32x4 __attribute__((ext_vector_type(4)));

__device__ __forceinline__ void fast_sincos(float x, float& s, float& c) {
    // gfx950 v_sin/v_cos take REVOLUTIONS. rev err <= |x|*2^-24 — negligible here.
    float rev = x * 0.15915494309189535f;
    rev -= rintf(rev);
    s = __builtin_amdgcn_sinf(rev);
    c = __builtin_amdgcn_cosf(rev);
}

__device__ __forceinline__ int cell_of(float x) {
    int c = (int)(x * 8.0f);
    return min(NCELL1 - 1, max(0, c));
}

// ---------------- ws layout (bytes) ----------------
static const size_t OFF_CSTART_I = 0;                      // 520 ints (513 used)
static const size_t OFF_SPTS_B   = 520 * 4;                // 2080 (16B aligned)
static const size_t OFF_CST_B    = OFF_SPTS_B + (size_t)N_PTS * 16;   // 133152
// csT: [768][8192] f16, SORTED point order. row d<384 = cos_d, row 384+d = sin_d.
static const size_t WS_FULL_B    = OFF_CST_B + (size_t)2 * ENC * N_PTS * 2 + 1024; // ~12.72MB

// ---------------- K1: count + scan + scatter, one block (proven in R7) ----------------
__global__ __launch_bounds__(1024) void k_prep(const float* __restrict__ pts,
                                               int* __restrict__ cell_start_g,
                                               float4* __restrict__ spts) {
    __shared__ int cnt[NCELLS];
    __shared__ int sc[NCELLS];
    __shared__ int cur[NCELLS];
    const int t = threadIdx.x;
    if (t < NCELLS) cnt[t] = 0;
    __syncthreads();

    int   cids[8];
    float xs[8], ys[8], zs[8];
    #pragma unroll
    for (int k = 0; k < 8; ++k) {
        int i = t + k * 1024;
        float x = pts[3 * i + 0], y = pts[3 * i + 1], z = pts[3 * i + 2];
        xs[k] = x; ys[k] = y; zs[k] = z;
        int cid = (cell_of(x) << 6) | (cell_of(y) << 3) | cell_of(z);
        cids[k] = cid;
        atomicAdd(&cnt[cid], 1);
    }
    __syncthreads();
    if (t < NCELLS) sc[t] = cnt[t];
    __syncthreads();
    for (int off = 1; off < NCELLS; off <<= 1) {
        int v = 0;
        if (t < NCELLS && t >= off) v = sc[t - off];
        __syncthreads();
        if (t < NCELLS) sc[t] += v;
        __syncthreads();
    }
    if (t < NCELLS) {
        int excl = sc[t] - cnt[t];
        cell_start_g[t] = excl;
        cur[t] = excl;
    }
    if (t == 0) cell_start_g[NCELLS] = N_PTS;
    __syncthreads();
    #pragma unroll
    for (int k = 0; k < 8; ++k) {
        int i = t + k * 1024;
        int pos = atomicAdd(&cur[cids[k]], 1);
        spts[pos] = make_float4(xs[k], ys[k], zs[k], __int_as_float(i));
    }
}

// ---------------- K2: csT[d][j]=cos, csT[384+d][j]=sin (f16, sorted order) ----------------
__global__ __launch_bounds__(NTHREAD) void k_encode(const float4* __restrict__ spts,
                                                    const float* __restrict__ A,
                                                    unsigned short* __restrict__ csT) {
    const int d = blockIdx.x;          // 0..383
    const int t = threadIdx.x;
    const float a0 = A[d], a1 = A[ENC + d], a2 = A[2 * ENC + d];
    for (int j = t; j < N_PTS; j += NTHREAD) {
        float4 P = spts[j];
        float qx = __fdiv_rn(P.x, RADIUS);
        float qy = __fdiv_rn(P.y, RADIUS);
        float qz = __fdiv_rn(P.z, RADIUS);
        float pa = fmaf(qz, a2, fmaf(qy, a1, qx * a0));
        float s, c;
        fast_sincos(pa, s, c);
        csT[(size_t)d * N_PTS + j]          = __half_as_ushort(__float2half_rn(c));
        csT[(size_t)(ENC + d) * N_PTS + j]  = __half_as_ushort(__float2half_rn(s));
    }
}

// ---------------- K3: per-cell masked GEMM via MFMA ----------------
__global__ __launch_bounds__(NTHREAD) void k_main(const float4* __restrict__ spts,
                                                  const int* __restrict__ cell_start,
                                                  const unsigned short* __restrict__ csT,
                                                  const float* __restrict__ A,
                                                  float* __restrict__ out, int out_mode) {
    // XCD-chunked swizzle: 64 consecutive cells per XCD (candidate windows share L2)
    const int cidx = blockIdx.x;
    const int cell = (cidx & 7) * 64 + (cidx >> 3);
    const int t = threadIdx.x;
    const int lane = t & 63;
    const int wv  = t >> 6;      // 0..5 : wave owns dims [64w, 64w+64)
    const int l15 = lane & 15;
    const int kq  = lane >> 4;   // 0..3

    __shared__ int    runs_lo[9], runs_hi[9];
    __shared__ float4 own_l[32];
    __shared__ __align__(16) unsigned short mb[2][2][16][32];  // [dbuf][tile][own][cand]
    __shared__ float  normw[6][16];
    __shared__ float  scale_l[16];

    const int o_lo = cell_start[cell];
    const int o_hi = cell_start[cell + 1];
    const int n_own = o_hi - o_lo;
    if (n_own <= 0) return;

    const int cx = cell >> 6, cy = (cell >> 3) & 7, cz = cell & 7;
    if (t < 9) {
        int dx = t / 3 - 1, dy = t % 3 - 1;
        int cxx = cx + dx, cyy = cy + dy;
        int lo = 0, hi = 0;
        if (cxx >= 0 && cxx <= 7 && cyy >= 0 && cyy <= 7) {
            int base = (cxx * 8 + cyy) * 8;
            int zlo = max(cz - 1, 0), zhi = min(cz + 1, 7);
            lo = cell_start[base + zlo];
            hi = cell_start[base + zhi + 1];
        }
        runs_lo[t] = lo; runs_hi[t] = hi;
    }

    const double R2 = (double)0.12 * (double)0.12;
    const float R2_LO = 0.0144f - 1e-6f;
    const float R2_HI = 0.0144f + 1e-6f;

    for (int base = 0; base < n_own; base += 32) {
        __syncthreads();                 // runs ready (1st iter) / own_l readers done
        if (t < 32) {
            int idx = o_lo + base + t;
            own_l[t] = (idx < o_hi) ? spts[idx]
                                    : make_float4(1e9f, 1e9f, 1e9f, __int_as_float(-1));
        }
        __syncthreads();
        const bool two = (n_own - base) > 16;
        const int nent = two ? 1024 : 512;

        f32x4 z; z[0] = 0.f; z[1] = 0.f; z[2] = 0.f; z[3] = 0.f;
        f32x4 aC0[4] = {z, z, z, z}, aS0[4] = {z, z, z, z};
        f32x4 aC1[4] = {z, z, z, z}, aS1[4] = {z, z, z, z};

        int cur = 0;
        for (int r = 0; r < 9; ++r) {
            const int rlo = runs_lo[r], rhi = runs_hi[r];
            if (rhi <= rlo) continue;
            const int jA0 = rlo & ~7;                 // 8-align for 16B B-loads
            const int nst = (rhi - jA0 + 31) >> 5;
            for (int st = 0; st < nst; ++st) {
                const int jA = jA0 + (st << 5);
                // ---- build 0/1 mask (classification identical to R5-R7) ----
                for (int e = t; e < nent; e += NTHREAD) {
                    const int tl = e >> 9, i = (e >> 5) & 15, k = e & 31;
                    const int j = jA + k;
                    unsigned short mv = 0;
                    if (j >= rlo && j < rhi) {
                        float4 Pj = spts[j];
                        float4 Pi = own_l[tl * 16 + i];
                        float fdx = Pj.x - Pi.x, fdy = Pj.y - Pi.y, fdz = Pj.z - Pi.z;
                        float d2f = fmaf(fdx, fdx, fmaf(fdy, fdy, fdz * fdz));
                        bool isnb = false;
                        if (d2f < R2_LO) {
                            isnb = true;
                        } else if (d2f <= R2_HI) {
                            double ddx = (double)Pj.x - (double)Pi.x;
                            double ddy = (double)Pj.y - (double)Pi.y;
                            double ddz = (double)Pj.z - (double)Pi.z;
                            isnb = (ddx * ddx + ddy * ddy + ddz * ddz) < R2;
                        }
                        if (isnb) mv = 0x3C00;        // f16 1.0
                    }
                    mb[cur][tl][i][k] = mv;
                }
                __syncthreads();
                // ---- MFMA: D[own][dim] += mask(16x32) * csT-slab(32x16) ----
                f16x8 af0 = *(const f16x8*)&mb[cur][0][l15][kq * 8];
                f16x8 af1;
                if (two) af1 = *(const f16x8*)&mb[cur][1][l15][kq * 8];
                const unsigned short* bptr = csT + jA + kq * 8;
                #pragma unroll
                for (int e2 = 0; e2 < 4; ++e2) {
                    const int d = wv * 64 + e2 * 16 + l15;
                    f16x8 bc = *(const f16x8*)(bptr + (size_t)d * N_PTS);
                    f16x8 bs = *(const f16x8*)(bptr + (size_t)(ENC + d) * N_PTS);
                    aC0[e2] = __builtin_amdgcn_mfma_f32_16x16x32_f16(af0, bc, aC0[e2], 0, 0, 0);
                    aS0[e2] = __builtin_amdgcn_mfma_f32_16x16x32_f16(af0, bs, aS0[e2], 0, 0, 0);
                    if (two) {
                        aC1[e2] = __builtin_amdgcn_mfma_f32_16x16x32_f16(af1, bc, aC1[e2], 0, 0, 0);
                        aS1[e2] = __builtin_amdgcn_mfma_f32_16x16x32_f16(af1, bs, aS1[e2], 0, 0, 0);
                    }
                }
                cur ^= 1;
            }
        }

        // ---- epilogue per own-tile: norm (phase-invariant), rotate, scale, store ----
        auto finish = [&](f32x4* aC, f32x4* aS, int tl) {
            __syncthreads();             // protect normw/scale_l reuse
            float np[4];
            #pragma unroll
            for (int reg = 0; reg < 4; ++reg) {
                float v = 0.f;
                #pragma unroll
                for (int e2 = 0; e2 < 4; ++e2)
                    v += aC[e2][reg] * aC[e2][reg] + aS[e2][reg] * aS[e2][reg];
                #pragma unroll
                for (int w = 1; w <= 8; w <<= 1) v += __shfl_xor(v, w);
                np[reg] = v;             // sum over this wave's 16 cols (c+s)
            }
            if (l15 == 0) {
                #pragma unroll
                for (int reg = 0; reg < 4; ++reg) normw[wv][kq * 4 + reg] = np[reg];
            }
            __syncthreads();
            if (t < 16) {
                float tot = normw[0][t] + normw[1][t] + normw[2][t]
                          + normw[3][t] + normw[4][t] + normw[5][t];
                scale_l[t] = sqrtf(384.0f / tot);
            }
            __syncthreads();
            #pragma unroll
            for (int e2 = 0; e2 < 4; ++e2) {
                const int d = wv * 64 + e2 * 16 + l15;
                const float a0 = A[d], a1 = A[ENC + d], a2 = A[2 * ENC + d];
                #pragma unroll
                for (int reg = 0; reg < 4; ++reg) {
                    const int i = kq * 4 + reg;      // C/D row = (lane>>4)*4 + reg [m89]
                    float4 Pi = own_l[tl * 16 + i];
                    int o = __float_as_int(Pi.w);
                    if (o >= 0) {
                        float qx = __fdiv_rn(Pi.x, RADIUS);
                        float qy = __fdiv_rn(Pi.y, RADIUS);
                        float qz = __fdiv_rn(Pi.z, RADIUS);
                        float pa = fmaf(qz, a2, fmaf(qy, a1, qx * a0));
                        float sv, cv;
                        fast_sincos(pa, sv, cv);
                        float Gr = aC[e2][reg], Gi = aS[e2][reg];
                        float sc = scale_l[i];
                        float re = (Gr * cv + Gi * sv) * sc;
                        float im = (Gi * cv - Gr * sv) * sc;
                        if (out_mode == 0) {
                            out[(size_t)o * ENC + d] = re;
                        } else {
                            reinterpret_cast<float2*>(out)[(size_t)o * ENC + d] =
                                make_float2(re, im);
                        }
                    }
                }
            }
        };
        finish(aC0, aS0, 0);
        if (two) finish(aC1, aS1, 1);
    }
}

// ---------------- last-resort all-pairs (ws too small; effectively dead) ----------------
__global__ __launch_bounds__(NTHREAD) void vecKM_allpairs(const float* __restrict__ pts,
                                                          const float* __restrict__ A,
                                                          float* __restrict__ out, int out_mode) {
    const int i = blockIdx.x;
    const int t = threadIdx.x;
    __shared__ float nb_x[512], nb_y[512], nb_z[512];
    __shared__ int nb_cnt;
    __shared__ float red[8];
    if (t == 0) nb_cnt = 0;
    __syncthreads();
    const float xi = pts[3 * i + 0], yi = pts[3 * i + 1], zi = pts[3 * i + 2];
    const double dxi = xi, dyi = yi, dzi = zi;
    const double R2 = (double)0.12 * (double)0.12;
    const float R2_LO = 0.0144f - 1e-6f, R2_HI = 0.0144f + 1e-6f;
    const int lane = t & 63;
    for (int jb = 0; jb < N_PTS; jb += NTHREAD) {
        const int j = jb + t;
        bool isnb = false;
        float xj = 0.f, yj = 0.f, zj = 0.f;
        if (j < N_PTS) {
            xj = pts[3 * j + 0]; yj = pts[3 * j + 1]; zj = pts[3 * j + 2];
            float fdx = xj - xi, fdy = yj - yi, fdz = zj - zi;
            float d2f = fmaf(fdx, fdx, fmaf(fdy, fdy, fdz * fdz));
            if (d2f < R2_LO) isnb = true;
            else if (d2f <= R2_HI) {
                double dx = (double)xj - dxi, dy = (double)yj - dyi, dz = (double)zj - dzi;
                isnb = (dx * dx + dy * dy + dz * dz) < R2;
            }
        }
        unsigned long long mask = __ballot(isnb);
        if (mask) {
            int leader = __ffsll((long long)mask) - 1;
            int basep = 0;
            if (lane == leader) basep = atomicAdd(&nb_cnt, __popcll(mask));
            basep = __shfl(basep, leader);
            if (isnb) {
                int pos = basep + __popcll(mask & ((1ull << lane) - 1ull));
                if (pos < 512) {
                    nb_x[pos] = (xj - xi) * (1.0f / 0.12f);
                    nb_y[pos] = (yj - yi) * (1.0f / 0.12f);
                    nb_z[pos] = (zj - zi) * (1.0f / 0.12f);
                }
            }
        }
    }
    __syncthreads();
    const int nn = min(nb_cnt, 512);
    const float a0 = A[t], a1 = A[ENC + t], a2 = A[2 * ENC + t];
    float gr = 0.f, gi = 0.f;
    #pragma unroll 4
    for (int m = 0; m < nn; ++m) {
        float pa = fmaf(nb_z[m], a2, fmaf(nb_y[m], a1, nb_x[m] * a0));
        float sv, cv;
        fast_sincos(pa, sv, cv);
        gr += cv; gi += sv;
    }
    float m2 = fmaf(gr, gr, gi * gi);
    #pragma unroll
    for (int off = 32; off > 0; off >>= 1) m2 += __shfl_down(m2, off);
    const int wid = t >> 6;
    if (lane == 0) red[wid] = m2;
    __syncthreads();
    if (t == 0) {
        float tot = 0.f;
        for (int w = 0; w < NTHREAD / 64; ++w) tot += red[w];
        red[7] = tot;
    }
    __syncthreads();
    const float scale = sqrtf(384.0f / red[7]);
    const float re = gr * scale, im = gi * scale;
    if (out_mode == 0) out[i * ENC + t] = re;
    else ((float2*)out)[i * ENC + t] = make_float2(re, im);
}

extern "C" void kernel_launch(void* const* d_in, const int* in_sizes, int n_in,
                              void* d_out, int out_size, void* d_ws, size_t ws_size,
                              hipStream_t stream) {
    const float* pts = (const float*)d_in[0];
    const float* A   = (const float*)d_in[1];
    float* out = (float*)d_out;
    const int out_mode = (out_size >= 2 * N_PTS * ENC) ? 1 : 0;

    if (ws_size >= WS_FULL_B) {
        int*            cell_start = (int*)d_ws + OFF_CSTART_I;
        float4*         spts       = (float4*)((char*)d_ws + OFF_SPTS_B);
        unsigned short* csT        = (unsigned short*)((char*)d_ws + OFF_CST_B);

        k_prep<<<1, 1024, 0, stream>>>(pts, cell_start, spts);
        k_encode<<<ENC, NTHREAD, 0, stream>>>(spts, A, csT);
        k_main<<<NCELLS, NTHREAD, 0, stream>>>(spts, cell_start, csT, A, out, out_mode);
    } else {
        vecKM_allpairs<<<N_PTS, NTHREAD, 0, stream>>>(pts, A, out, out_mode);
    }
}